// Round 5
// baseline (394.994 us; speedup 1.0000x reference)
//
#include <hip/hip_runtime.h>

#define NHEADS 12
#define SEQ    1024
#define HDIM   768
#define DHEAD  64
#define BH_TOT 48
#define EPSN   1e-6f

typedef __attribute__((ext_vector_type(8))) short    bf8;  // 8 bf16 (4 VGPRs) MFMA A/B frag
typedef __attribute__((ext_vector_type(4))) float    fx4;  // MFMA C/D frag / float4
typedef __attribute__((ext_vector_type(4))) _Float16 h4;   // 4 f16 (2 VGPRs) 16x16x16 frag

#define SZT 3145728u   // 48*1024*64 elements (one head-split tensor)
#define WSZ 589824u    // 768*768 elements (one weight matrix)

__device__ __forceinline__ float bf2f(unsigned short h) {
  union { unsigned int u; float f; } v; v.u = ((unsigned int)h) << 16; return v.f;
}
__device__ __forceinline__ unsigned short f2bf(float f) {
  union { float f; unsigned int u; } v; v.f = f;
  unsigned int u = v.u;
  return (unsigned short)((u + 0x7FFFu + ((u >> 16) & 1u)) >> 16);
}

// async global->LDS, 16B per lane; LDS dest = wave-uniform base + lane*16.
typedef __attribute__((address_space(3))) unsigned int lds_u32;
typedef __attribute__((address_space(1))) const unsigned int glb_u32;
__device__ __forceinline__ void gld16(const unsigned short* g, unsigned short* l) {
  __builtin_amdgcn_global_load_lds((glb_u32*)g, (lds_u32*)l, 16, 0, 0);
}

// ---------------------------------------------------------------------------
// One-shot f32 -> bf16 conversion of X (hs,te,se) and W (q,k,v,t,s) into ws.
// Layout (ushort units): hsb@5SZ teb@6SZ seb@7SZ  W[z]@8SZ + z*WSZ
// ---------------------------------------------------------------------------
__global__ void convert_kernel(const float* __restrict__ hs, const float* __restrict__ te,
                               const float* __restrict__ se,
                               const float* __restrict__ Wq, const float* __restrict__ Wk,
                               const float* __restrict__ Wv, const float* __restrict__ Wt,
                               const float* __restrict__ Ws2,
                               unsigned short* __restrict__ ws)
{
  const int z = blockIdx.y;
  const float* src;
  unsigned short* dst;
  int n;
  if (z < 3) {
    src = (z == 0) ? hs : (z == 1) ? te : se;
    dst = ws + (size_t)(5 + z) * SZT;
    n = 3145728;
  } else {
    src = (z == 3) ? Wq : (z == 4) ? Wk : (z == 5) ? Wv : (z == 6) ? Wt : Ws2;
    dst = ws + (size_t)8 * SZT + (size_t)(z - 3) * WSZ;
    n = 589824;
  }
  const int base = (blockIdx.x * 256 + threadIdx.x) * 8;
  if (base >= n) return;
  const fx4 a = *(const fx4*)(src + base);
  const fx4 b = *(const fx4*)(src + base + 4);
  bf8 o;
#pragma unroll
  for (int j = 0; j < 4; ++j) { o[j] = (short)f2bf(a[j]); o[4 + j] = (short)f2bf(b[j]); }
  *(bf8*)(dst + base) = o;
}

// ---------------------------------------------------------------------------
// Fused Q/K/V projection: one X staging feeds 3 weight tiles (48 MFMA/wave per
// barrier). out = hs @ W{q,k,v}^T + b, head-split; V written f16-transposed.
// ---------------------------------------------------------------------------
__global__ __launch_bounds__(256, 2)
void proj_qkv_kernel(unsigned short* __restrict__ ws,
                     const float* __restrict__ bq, const float* __restrict__ bk,
                     const float* __restrict__ bv)
{
  __shared__ unsigned short Xs[2][4096];
  __shared__ unsigned short Wqs[2][4096];
  __shared__ unsigned short Wks[2][4096];
  __shared__ unsigned short Wvs[2][4096];

  const unsigned short* X  = ws + (size_t)5 * SZT;
  const unsigned short* Wq = ws + (size_t)8 * SZT;
  const unsigned short* Wk = Wq + WSZ;
  const unsigned short* Wv = Wq + 2 * WSZ;

  const int tid   = threadIdx.x;
  const int lane  = tid & 63;
  const int wid   = tid >> 6;
  const int wm    = wid >> 1, wn = wid & 1;
  const int colid = lane & 15, quad = lane >> 4;
  const int m0 = blockIdx.y * 128, n0 = blockIdx.x * 128;

  auto stage = [&](int kt, int pb) {
#pragma unroll
    for (int i = 0; i < 2; ++i) {
      const int slot = i * 256 + tid;        // 0..511, 16B each
      const int row = slot >> 2, ch = slot & 3;
      const int goff = kt + ch * 8;
      gld16(X  + (m0 + row) * HDIM + goff, &Xs[pb][slot * 8]);
      gld16(Wq + (n0 + row) * HDIM + goff, &Wqs[pb][slot * 8]);
      gld16(Wk + (n0 + row) * HDIM + goff, &Wks[pb][slot * 8]);
      gld16(Wv + (n0 + row) * HDIM + goff, &Wvs[pb][slot * 8]);
    }
  };

  fx4 acc[3][4][4];
#pragma unroll
  for (int t = 0; t < 3; ++t)
#pragma unroll
    for (int i = 0; i < 4; ++i)
#pragma unroll
      for (int j = 0; j < 4; ++j) acc[t][i][j] = (fx4){0.f, 0.f, 0.f, 0.f};

  stage(0, 0);
  __syncthreads();

  for (int it = 0; it < 24; ++it) {
    const int pb = it & 1;
    if (it + 1 < 24) stage((it + 1) * 32, pb ^ 1);

    bf8 af[4];
#pragma unroll
    for (int i = 0; i < 4; ++i)
      af[i] = *(const bf8*)&Xs[pb][(wm * 64 + i * 16 + colid) * 32 + quad * 8];
#pragma unroll
    for (int j = 0; j < 4; ++j) {
      const int boff = (wn * 64 + j * 16 + colid) * 32 + quad * 8;
      const bf8 bqj = *(const bf8*)&Wqs[pb][boff];
      const bf8 bkj = *(const bf8*)&Wks[pb][boff];
      const bf8 bvj = *(const bf8*)&Wvs[pb][boff];
#pragma unroll
      for (int i = 0; i < 4; ++i) {
        acc[0][i][j] = __builtin_amdgcn_mfma_f32_16x16x32_bf16(af[i], bqj, acc[0][i][j], 0, 0, 0);
        acc[1][i][j] = __builtin_amdgcn_mfma_f32_16x16x32_bf16(af[i], bkj, acc[1][i][j], 0, 0, 0);
        acc[2][i][j] = __builtin_amdgcn_mfma_f32_16x16x32_bf16(af[i], bvj, acc[2][i][j], 0, 0, 0);
      }
    }
    __syncthreads();
  }

  // Epilogues. C/D layout: col=lane&15, row=quad*4+reg.
#pragma unroll
  for (int i = 0; i < 4; ++i) {
    const int r0 = m0 + wm * 64 + i * 16 + quad * 4;
    const int bb = r0 >> 10, s0 = r0 & 1023;
#pragma unroll
    for (int j = 0; j < 4; ++j) {
      const int c = n0 + wn * 64 + j * 16 + colid;
      const int h = c >> 6, d = c & 63;
      // Q
      {
        const float bvl = bq[c];
        unsigned short* op = ws + (((bb * NHEADS + h) * SEQ + s0) * DHEAD + d);
#pragma unroll
        for (int reg = 0; reg < 4; ++reg)
          op[reg * DHEAD] = f2bf(acc[0][i][j][reg] + bvl);
      }
      // K
      {
        const float bvl = bk[c];
        unsigned short* op = ws + (size_t)1 * SZT + (((bb * NHEADS + h) * SEQ + s0) * DHEAD + d);
#pragma unroll
        for (int reg = 0; reg < 4; ++reg)
          op[reg * DHEAD] = f2bf(acc[1][i][j][reg] + bvl);
      }
      // V -> f16, transposed: Vt[(bh*64+d)*1024 + s]
      {
        const float bvl = bv[c];
        h4 pk;
#pragma unroll
        for (int reg = 0; reg < 4; ++reg)
          pk[reg] = (_Float16)(acc[2][i][j][reg] + bvl);
        *(h4*)(void*)(ws + (size_t)4 * SZT
                        + ((size_t)((bb * NHEADS + h) * DHEAD + d)) * SEQ + s0) = pk;
      }
    }
  }
}

// ---------------------------------------------------------------------------
// T/S projection (plain 128x128 double-buffered): z=0 -> T, z=1 -> S.
// ---------------------------------------------------------------------------
__global__ __launch_bounds__(256, 3)
void proj_ts_kernel(unsigned short* __restrict__ ws,
                    const float* __restrict__ bt, const float* __restrict__ bs)
{
  __shared__ unsigned short Xs[2][4096];
  __shared__ unsigned short Ys[2][4096];

  const int z = blockIdx.z;
  const unsigned short* X = ws + (size_t)(6 + z) * SZT;            // teb / seb
  const unsigned short* W = ws + (size_t)8 * SZT + (size_t)(3 + z) * WSZ;
  const float* bias = z ? bs : bt;
  unsigned short* out = ws + (size_t)(2 + z) * SZT;                // Tb / Sb

  const int tid   = threadIdx.x;
  const int lane  = tid & 63;
  const int wid   = tid >> 6;
  const int wm    = wid >> 1, wn = wid & 1;
  const int colid = lane & 15, quad = lane >> 4;
  const int m0 = blockIdx.y * 128, n0 = blockIdx.x * 128;

  auto stage = [&](int kt, int pb) {
#pragma unroll
    for (int i = 0; i < 2; ++i) {
      const int slot = i * 256 + tid;
      const int row = slot >> 2, ch = slot & 3;
      gld16(X + (m0 + row) * HDIM + kt + ch * 8, &Xs[pb][slot * 8]);
      gld16(W + (n0 + row) * HDIM + kt + ch * 8, &Ys[pb][slot * 8]);
    }
  };

  fx4 acc[4][4];
#pragma unroll
  for (int i = 0; i < 4; ++i)
#pragma unroll
    for (int j = 0; j < 4; ++j) acc[i][j] = (fx4){0.f, 0.f, 0.f, 0.f};

  stage(0, 0);
  __syncthreads();

  for (int it = 0; it < 24; ++it) {
    const int pb = it & 1;
    if (it + 1 < 24) stage((it + 1) * 32, pb ^ 1);

    bf8 af[4], bfr[4];
#pragma unroll
    for (int i = 0; i < 4; ++i)
      af[i] = *(const bf8*)&Xs[pb][(wm * 64 + i * 16 + colid) * 32 + quad * 8];
#pragma unroll
    for (int j = 0; j < 4; ++j)
      bfr[j] = *(const bf8*)&Ys[pb][(wn * 64 + j * 16 + colid) * 32 + quad * 8];
#pragma unroll
    for (int i = 0; i < 4; ++i)
#pragma unroll
      for (int j = 0; j < 4; ++j)
        acc[i][j] = __builtin_amdgcn_mfma_f32_16x16x32_bf16(af[i], bfr[j], acc[i][j], 0, 0, 0);
    __syncthreads();
  }

#pragma unroll
  for (int i = 0; i < 4; ++i) {
    const int r0 = m0 + wm * 64 + i * 16 + quad * 4;
    const int bb = r0 >> 10, s0 = r0 & 1023;
#pragma unroll
    for (int j = 0; j < 4; ++j) {
      const int c = n0 + wn * 64 + j * 16 + colid;
      const int h = c >> 6, d = c & 63;
      const float bvl = bias[c];
      unsigned short* op = out + (((bb * NHEADS + h) * SEQ + s0) * DHEAD + d);
#pragma unroll
      for (int reg = 0; reg < 4; ++reg)
        op[reg * DHEAD] = f2bf(acc[i][j][reg] + bvl);
    }
  }
}

// ---------------------------------------------------------------------------
// Flash attention, barrier-free, XCD-swizzled.
// Swizzle: lin%8 picks the XCD (HW round-robin assumption); each XCD owns
// 6 bh, and all 16 q-blocks of a bh land on that XCD => hot K/T/S/V slab
// 6 x 512KB = 3MB fits the 4MB XCD L2 (was 24MB thrash).
// Transposed scores (C[key][q]) => per-lane softmax (2 shfl); P regs feed
// 16x16x16_f16 PV directly. All loads direct from global (L2-hit).
// ---------------------------------------------------------------------------
__global__ __launch_bounds__(256, 3)
void attn_kernel(const unsigned short* __restrict__ ws,
                 const float* __restrict__ maskb,
                 float* __restrict__ outb)
{
  const unsigned short* Qb  = ws;
  const unsigned short* GT0 = ws + (size_t)1 * SZT;   // K
  const unsigned short* GT1 = ws + (size_t)2 * SZT;   // T
  const unsigned short* GT2 = ws + (size_t)3 * SZT;   // S
  const _Float16* Vtf = (const _Float16*)(ws + (size_t)4 * SZT);

  const int tid   = threadIdx.x;
  const int lane  = tid & 63;
  const int w     = tid >> 6;
  const int colid = lane & 15, quad = lane >> 4;

  // XCD swizzle: bijection lin <-> (bh, qx) with XCD(lin)=lin&7 constant per bh.
  const int lin = blockIdx.y * 16 + blockIdx.x;
  const int xcd = lin & 7;
  const int g   = lin >> 3;            // 0..95
  const int bh  = xcd * 6 + (g % 6);
  const int qx  = g / 6;               // 0..15

  const int b  = bh / NHEADS, h = bh % NHEADS;
  const int q0 = qx * 64 + w * 16;
  const int base_h = bh * SEQ * DHEAD;

  // Invariant query-side B-frags: lane holds B[k=quad*8+j][n=colid] = Q[q0+colid][d]
  bf8 bqf[2], btf[2], bsf[2];
  {
    const int row = q0 + colid;
    const unsigned short* qp = Qb  + base_h + row * 64 + quad * 8;
    const unsigned short* tp = GT1 + base_h + row * 64 + quad * 8;
    const unsigned short* sp = GT2 + base_h + row * 64 + quad * 8;
    bqf[0] = *(const bf8*)qp;  bqf[1] = *(const bf8*)(qp + 32);
    btf[0] = *(const bf8*)tp;  btf[1] = *(const bf8*)(tp + 32);
    bsf[0] = *(const bf8*)sp;  bsf[1] = *(const bf8*)(sp + 32);
  }

  // Fused per-query scale: rs = 1/((|T_q|+eps)(|S_q|+eps)*8), for q = colid.
  float rs;
  {
    float t2 = 0.f, s2 = 0.f;
#pragma unroll
    for (int fr = 0; fr < 2; ++fr)
#pragma unroll
      for (int j = 0; j < 8; ++j) {
        const float tv = bf2f((unsigned short)btf[fr][j]);
        const float sv2 = bf2f((unsigned short)bsf[fr][j]);
        t2 += tv * tv; s2 += sv2 * sv2;
      }
    t2 += __shfl_xor(t2, 16); t2 += __shfl_xor(t2, 32);
    s2 += __shfl_xor(s2, 16); s2 += __shfl_xor(s2, 32);
    rs = 1.0f / ((sqrtf(t2) + EPSN) * (sqrtf(s2) + EPSN) * 8.0f);
  }

  float m_ = -1.0e30f, l_ = 0.f;
  fx4 o[4];
#pragma unroll
  for (int fd = 0; fd < 4; ++fd) o[fd] = (fx4){0.f, 0.f, 0.f, 0.f};
  const fx4 zero = (fx4){0.f, 0.f, 0.f, 0.f};

  for (int kb = 0; kb < SEQ; kb += 64) {
    // Early-issue V + mask (L2-hit; consumed after softmax / scores).
    h4 vv[4][4];
#pragma unroll
    for (int f = 0; f < 4; ++f)
#pragma unroll
      for (int fd = 0; fd < 4; ++fd)
        vv[f][fd] = *(const h4*)(Vtf + (size_t)(bh * DHEAD + fd * 16 + colid) * SEQ
                                     + kb + f * 16 + quad * 4);
    fx4 mk[4];
#pragma unroll
    for (int f = 0; f < 4; ++f)
      mk[f] = *(const fx4*)(maskb + b * SEQ + kb + f * 16 + quad * 4);

    // scores^T: A = K/T/S key rows (direct global), B = query regs.
    // C[key=quad*4+reg][q=colid].
    float sv[4][4];
#pragma unroll
    for (int f = 0; f < 4; ++f) {
      const int key = kb + f * 16 + colid;
      const unsigned short* kp  = GT0 + base_h + key * 64 + quad * 8;
      const unsigned short* tp  = GT1 + base_h + key * 64 + quad * 8;
      const unsigned short* spp = GT2 + base_h + key * 64 + quad * 8;
      const bf8 ak0 = *(const bf8*)kp,  ak1 = *(const bf8*)(kp + 32);
      const bf8 at0 = *(const bf8*)tp,  at1 = *(const bf8*)(tp + 32);
      const bf8 as0 = *(const bf8*)spp, as1 = *(const bf8*)(spp + 32);
      fx4 ab = __builtin_amdgcn_mfma_f32_16x16x32_bf16(ak0, bqf[0], zero, 0, 0, 0);
      ab = __builtin_amdgcn_mfma_f32_16x16x32_bf16(ak1, bqf[1], ab, 0, 0, 0);
      fx4 tt = __builtin_amdgcn_mfma_f32_16x16x32_bf16(at0, btf[0], zero, 0, 0, 0);
      tt = __builtin_amdgcn_mfma_f32_16x16x32_bf16(at1, btf[1], tt, 0, 0, 0);
      fx4 ss = __builtin_amdgcn_mfma_f32_16x16x32_bf16(as0, bsf[0], zero, 0, 0, 0);
      ss = __builtin_amdgcn_mfma_f32_16x16x32_bf16(as1, bsf[1], ss, 0, 0, 0);
#pragma unroll
      for (int reg = 0; reg < 4; ++reg)
        sv[f][reg] = (ab[reg] * tt[reg]) * ss[reg] * rs + mk[f][reg];
    }

    // Per-lane softmax for q=colid (16 in-lane scores + 2-shfl cross-quad reduce).
    float bm = sv[0][0];
#pragma unroll
    for (int f = 0; f < 4; ++f)
#pragma unroll
      for (int reg = 0; reg < 4; ++reg) bm = fmaxf(bm, sv[f][reg]);
    bm = fmaxf(bm, __shfl_xor(bm, 16));
    bm = fmaxf(bm, __shfl_xor(bm, 32));
    const float mn = fmaxf(m_, bm);
    const float alpha = __expf(m_ - mn);
    float rsum = 0.f;
    h4 pa[4];
#pragma unroll
    for (int f = 0; f < 4; ++f)
#pragma unroll
      for (int reg = 0; reg < 4; ++reg) {
        const float p = __expf(sv[f][reg] - mn);
        rsum += p;
        pa[f][reg] = (_Float16)p;
      }
    rsum += __shfl_xor(rsum, 16);
    rsum += __shfl_xor(rsum, 32);
    l_ = l_ * alpha + rsum;
    m_ = mn;

    // O rows are q=quad*4+reg: fetch their alpha from the lane with colid==row.
    float ar[4];
#pragma unroll
    for (int reg = 0; reg < 4; ++reg) ar[reg] = __shfl(alpha, quad * 4 + reg);
#pragma unroll
    for (int fd = 0; fd < 4; ++fd)
#pragma unroll
      for (int reg = 0; reg < 4; ++reg) o[fd][reg] *= ar[reg];

    // O += P.V : P regs are the 16x16x16 A-frag (m=q=colid, k=quad*4+reg).
#pragma unroll
    for (int f = 0; f < 4; ++f)
#pragma unroll
      for (int fd = 0; fd < 4; ++fd)
        o[fd] = __builtin_amdgcn_mfma_f32_16x16x16f16(pa[f], vv[f][fd], o[fd], 0, 0, 0);
  }

  // Epilogue: out[b, s, h*64+d] = O / l  (f32 out). O rows q=quad*4+reg.
  const float linv = 1.0f / l_;
  float ir[4];
#pragma unroll
  for (int reg = 0; reg < 4; ++reg) ir[reg] = __shfl(linv, quad * 4 + reg);
#pragma unroll
  for (int reg = 0; reg < 4; ++reg) {
    const int s = q0 + quad * 4 + reg;
#pragma unroll
    for (int fd = 0; fd < 4; ++fd)
      outb[(size_t)(b * SEQ + s) * HDIM + h * DHEAD + fd * 16 + colid] = o[fd][reg] * ir[reg];
  }
}

extern "C" void kernel_launch(void* const* d_in, const int* in_sizes, int n_in,
                              void* d_out, int out_size, void* d_ws, size_t ws_size,
                              hipStream_t stream)
{
  (void)in_sizes; (void)n_in; (void)out_size; (void)ws_size;
  const float* hs   = (const float*)d_in[0];
  const float* te   = (const float*)d_in[1];
  const float* se   = (const float*)d_in[2];
  const float* mask = (const float*)d_in[3];
  const float* Wq   = (const float*)d_in[4];
  const float* bq   = (const float*)d_in[5];
  const float* Wk   = (const float*)d_in[6];
  const float* bk   = (const float*)d_in[7];
  const float* Wv   = (const float*)d_in[8];
  const float* bv   = (const float*)d_in[9];
  const float* Wt   = (const float*)d_in[10];
  const float* bt   = (const float*)d_in[11];
  const float* Wsp  = (const float*)d_in[12];
  const float* bsp  = (const float*)d_in[13];
  float* out = (float*)d_out;
  unsigned short* ws = (unsigned short*)d_ws;

  // ws layout (ushort units): Qb@0 Kb@1SZ Tb@2SZ Sb@3SZ Vt(f16)@4SZ
  // convert-phase: hsb@5SZ teb@6SZ seb@7SZ W[5]@8SZ+z*WSZ (dead after proj)
  convert_kernel<<<dim3(1536, 8), 256, 0, stream>>>(hs, te, se, Wq, Wk, Wv, Wt, Wsp, ws);
  proj_qkv_kernel<<<dim3(6, 32), 256, 0, stream>>>(ws, bq, bk, bv);
  proj_ts_kernel<<<dim3(6, 32, 2), 256, 0, stream>>>(ws, bt, bsp);
  attn_kernel<<<dim3(16, BH_TOT), 256, 0, stream>>>(ws, mask, out);
}

// Round 6
// 297.787 us; speedup vs baseline: 1.3264x; 1.3264x over previous
//
#include <hip/hip_runtime.h>

#define NHEADS 12
#define SEQ    1024
#define HDIM   768
#define DHEAD  64
#define BH_TOT 48
#define EPSN   1e-6f

typedef __attribute__((ext_vector_type(8))) short    bf8;  // 8 bf16 (4 VGPRs) MFMA A/B frag
typedef __attribute__((ext_vector_type(4))) float    fx4;  // MFMA C/D frag / float4
typedef __attribute__((ext_vector_type(4))) _Float16 h4;   // 4 f16 (2 VGPRs) 16x16x16 frag

#define SZT 3145728u   // 48*1024*64 elements (one head-split tensor)
#define WSZ 589824u    // 768*768 elements (one weight matrix)

__device__ __forceinline__ float bf2f(unsigned short h) {
  union { unsigned int u; float f; } v; v.u = ((unsigned int)h) << 16; return v.f;
}
__device__ __forceinline__ unsigned short f2bf(float f) {
  union { float f; unsigned int u; } v; v.f = f;
  unsigned int u = v.u;
  return (unsigned short)((u + 0x7FFFu + ((u >> 16) & 1u)) >> 16);
}

// async global->LDS, 16B per lane; LDS dest = wave-uniform base + lane*16.
typedef __attribute__((address_space(3))) unsigned int lds_u32;
typedef __attribute__((address_space(1))) const unsigned int glb_u32;
__device__ __forceinline__ void gld16(const unsigned short* g, unsigned short* l) {
  __builtin_amdgcn_global_load_lds((glb_u32*)g, (lds_u32*)l, 16, 0, 0);
}

// ---------------------------------------------------------------------------
// One-shot f32 -> bf16 conversion of X (hs,te,se) and W (q,k,v,t,s) into ws.
// Layout (ushort units): hsb@5SZ teb@6SZ seb@7SZ  W[z]@8SZ + z*WSZ
// ---------------------------------------------------------------------------
__global__ void convert_kernel(const float* __restrict__ hs, const float* __restrict__ te,
                               const float* __restrict__ se,
                               const float* __restrict__ Wq, const float* __restrict__ Wk,
                               const float* __restrict__ Wv, const float* __restrict__ Wt,
                               const float* __restrict__ Ws2,
                               unsigned short* __restrict__ ws)
{
  const int z = blockIdx.y;
  const float* src;
  unsigned short* dst;
  int n;
  if (z < 3) {
    src = (z == 0) ? hs : (z == 1) ? te : se;
    dst = ws + (size_t)(5 + z) * SZT;
    n = 3145728;
  } else {
    src = (z == 3) ? Wq : (z == 4) ? Wk : (z == 5) ? Wv : (z == 6) ? Wt : Ws2;
    dst = ws + (size_t)8 * SZT + (size_t)(z - 3) * WSZ;
    n = 589824;
  }
  const int base = (blockIdx.x * 256 + threadIdx.x) * 8;
  if (base >= n) return;
  const fx4 a = *(const fx4*)(src + base);
  const fx4 b = *(const fx4*)(src + base + 4);
  bf8 o;
#pragma unroll
  for (int j = 0; j < 4; ++j) { o[j] = (short)f2bf(a[j]); o[4 + j] = (short)f2bf(b[j]); }
  *(bf8*)(dst + base) = o;
}

// ---------------------------------------------------------------------------
// Fused Q/K/V projection: one X staging feeds 3 weight tiles.
// out = hs @ W{q,k,v}^T + b, head-split; V written f16-transposed.
// ---------------------------------------------------------------------------
__global__ __launch_bounds__(256, 2)
void proj_qkv_kernel(unsigned short* __restrict__ ws,
                     const float* __restrict__ bq, const float* __restrict__ bk,
                     const float* __restrict__ bv)
{
  __shared__ unsigned short Xs[2][4096];
  __shared__ unsigned short Wqs[2][4096];
  __shared__ unsigned short Wks[2][4096];
  __shared__ unsigned short Wvs[2][4096];

  const unsigned short* X  = ws + (size_t)5 * SZT;
  const unsigned short* Wq = ws + (size_t)8 * SZT;
  const unsigned short* Wk = Wq + WSZ;
  const unsigned short* Wv = Wq + 2 * WSZ;

  const int tid   = threadIdx.x;
  const int lane  = tid & 63;
  const int wid   = tid >> 6;
  const int wm    = wid >> 1, wn = wid & 1;
  const int colid = lane & 15, quad = lane >> 4;
  const int m0 = blockIdx.y * 128, n0 = blockIdx.x * 128;

  auto stage = [&](int kt, int pb) {
#pragma unroll
    for (int i = 0; i < 2; ++i) {
      const int slot = i * 256 + tid;
      const int row = slot >> 2, ch = slot & 3;
      const int goff = kt + ch * 8;
      gld16(X  + (m0 + row) * HDIM + goff, &Xs[pb][slot * 8]);
      gld16(Wq + (n0 + row) * HDIM + goff, &Wqs[pb][slot * 8]);
      gld16(Wk + (n0 + row) * HDIM + goff, &Wks[pb][slot * 8]);
      gld16(Wv + (n0 + row) * HDIM + goff, &Wvs[pb][slot * 8]);
    }
  };

  fx4 acc[3][4][4];
#pragma unroll
  for (int t = 0; t < 3; ++t)
#pragma unroll
    for (int i = 0; i < 4; ++i)
#pragma unroll
      for (int j = 0; j < 4; ++j) acc[t][i][j] = (fx4){0.f, 0.f, 0.f, 0.f};

  stage(0, 0);
  __syncthreads();

  for (int it = 0; it < 24; ++it) {
    const int pb = it & 1;
    if (it + 1 < 24) stage((it + 1) * 32, pb ^ 1);

    bf8 af[4];
#pragma unroll
    for (int i = 0; i < 4; ++i)
      af[i] = *(const bf8*)&Xs[pb][(wm * 64 + i * 16 + colid) * 32 + quad * 8];
#pragma unroll
    for (int j = 0; j < 4; ++j) {
      const int boff = (wn * 64 + j * 16 + colid) * 32 + quad * 8;
      const bf8 bqj = *(const bf8*)&Wqs[pb][boff];
      const bf8 bkj = *(const bf8*)&Wks[pb][boff];
      const bf8 bvj = *(const bf8*)&Wvs[pb][boff];
#pragma unroll
      for (int i = 0; i < 4; ++i) {
        acc[0][i][j] = __builtin_amdgcn_mfma_f32_16x16x32_bf16(af[i], bqj, acc[0][i][j], 0, 0, 0);
        acc[1][i][j] = __builtin_amdgcn_mfma_f32_16x16x32_bf16(af[i], bkj, acc[1][i][j], 0, 0, 0);
        acc[2][i][j] = __builtin_amdgcn_mfma_f32_16x16x32_bf16(af[i], bvj, acc[2][i][j], 0, 0, 0);
      }
    }
    __syncthreads();
  }

#pragma unroll
  for (int i = 0; i < 4; ++i) {
    const int r0 = m0 + wm * 64 + i * 16 + quad * 4;
    const int bb = r0 >> 10, s0 = r0 & 1023;
#pragma unroll
    for (int j = 0; j < 4; ++j) {
      const int c = n0 + wn * 64 + j * 16 + colid;
      const int h = c >> 6, d = c & 63;
      {
        const float bvl = bq[c];
        unsigned short* op = ws + (((bb * NHEADS + h) * SEQ + s0) * DHEAD + d);
#pragma unroll
        for (int reg = 0; reg < 4; ++reg)
          op[reg * DHEAD] = f2bf(acc[0][i][j][reg] + bvl);
      }
      {
        const float bvl = bk[c];
        unsigned short* op = ws + (size_t)1 * SZT + (((bb * NHEADS + h) * SEQ + s0) * DHEAD + d);
#pragma unroll
        for (int reg = 0; reg < 4; ++reg)
          op[reg * DHEAD] = f2bf(acc[1][i][j][reg] + bvl);
      }
      {
        const float bvl = bv[c];
        h4 pk;
#pragma unroll
        for (int reg = 0; reg < 4; ++reg)
          pk[reg] = (_Float16)(acc[2][i][j][reg] + bvl);
        *(h4*)(void*)(ws + (size_t)4 * SZT
                        + ((size_t)((bb * NHEADS + h) * DHEAD + d)) * SEQ + s0) = pk;
      }
    }
  }
}

// ---------------------------------------------------------------------------
// T/S projection (plain 128x128 double-buffered): z=0 -> T, z=1 -> S.
// ---------------------------------------------------------------------------
__global__ __launch_bounds__(256, 3)
void proj_ts_kernel(unsigned short* __restrict__ ws,
                    const float* __restrict__ bt, const float* __restrict__ bs)
{
  __shared__ unsigned short Xs[2][4096];
  __shared__ unsigned short Ys[2][4096];

  const int z = blockIdx.z;
  const unsigned short* X = ws + (size_t)(6 + z) * SZT;
  const unsigned short* W = ws + (size_t)8 * SZT + (size_t)(3 + z) * WSZ;
  const float* bias = z ? bs : bt;
  unsigned short* out = ws + (size_t)(2 + z) * SZT;

  const int tid   = threadIdx.x;
  const int lane  = tid & 63;
  const int wid   = tid >> 6;
  const int wm    = wid >> 1, wn = wid & 1;
  const int colid = lane & 15, quad = lane >> 4;
  const int m0 = blockIdx.y * 128, n0 = blockIdx.x * 128;

  auto stage = [&](int kt, int pb) {
#pragma unroll
    for (int i = 0; i < 2; ++i) {
      const int slot = i * 256 + tid;
      const int row = slot >> 2, ch = slot & 3;
      gld16(X + (m0 + row) * HDIM + kt + ch * 8, &Xs[pb][slot * 8]);
      gld16(W + (n0 + row) * HDIM + kt + ch * 8, &Ys[pb][slot * 8]);
    }
  };

  fx4 acc[4][4];
#pragma unroll
  for (int i = 0; i < 4; ++i)
#pragma unroll
    for (int j = 0; j < 4; ++j) acc[i][j] = (fx4){0.f, 0.f, 0.f, 0.f};

  stage(0, 0);
  __syncthreads();

  for (int it = 0; it < 24; ++it) {
    const int pb = it & 1;
    if (it + 1 < 24) stage((it + 1) * 32, pb ^ 1);

    bf8 af[4], bfr[4];
#pragma unroll
    for (int i = 0; i < 4; ++i)
      af[i] = *(const bf8*)&Xs[pb][(wm * 64 + i * 16 + colid) * 32 + quad * 8];
#pragma unroll
    for (int j = 0; j < 4; ++j)
      bfr[j] = *(const bf8*)&Ys[pb][(wn * 64 + j * 16 + colid) * 32 + quad * 8];
#pragma unroll
    for (int i = 0; i < 4; ++i)
#pragma unroll
      for (int j = 0; j < 4; ++j)
        acc[i][j] = __builtin_amdgcn_mfma_f32_16x16x32_bf16(af[i], bfr[j], acc[i][j], 0, 0, 0);
    __syncthreads();
  }

#pragma unroll
  for (int i = 0; i < 4; ++i) {
    const int r0 = m0 + wm * 64 + i * 16 + quad * 4;
    const int bb = r0 >> 10, s0 = r0 & 1023;
#pragma unroll
    for (int j = 0; j < 4; ++j) {
      const int c = n0 + wn * 64 + j * 16 + colid;
      const int h = c >> 6, d = c & 63;
      const float bvl = bias[c];
      unsigned short* op = out + (((bb * NHEADS + h) * SEQ + s0) * DHEAD + d);
#pragma unroll
      for (int reg = 0; reg < 4; ++reg)
        op[reg * DHEAD] = f2bf(acc[i][j][reg] + bvl);
    }
  }
}

// ---------------------------------------------------------------------------
// Flash attention, wave = 64 q (4 groups of 16), single-wave 64-thread blocks,
// grid 768 = 3 waves/CU, XCD-swizzled (bh pinned to one XCD => 3MB L2 slab).
// K/T/S/V/mask tile loads issued ONCE per tile, pinned above compute by
// sched_barrier(0), amortized over 4 q-groups (160 MFMA per 44 loads).
// Transposed scores => per-lane softmax (2 shfl per group); P regs feed
// 16x16x16_f16 PV directly. No LDS, no barriers.
// ---------------------------------------------------------------------------
__global__ __launch_bounds__(64, 1)
void attn_kernel(const unsigned short* __restrict__ ws,
                 const float* __restrict__ maskb,
                 float* __restrict__ outb)
{
  const unsigned short* Qb  = ws;
  const unsigned short* GT0 = ws + (size_t)1 * SZT;   // K
  const unsigned short* GT1 = ws + (size_t)2 * SZT;   // T
  const unsigned short* GT2 = ws + (size_t)3 * SZT;   // S
  const _Float16* Vtf = (const _Float16*)(ws + (size_t)4 * SZT);

  const int lane  = threadIdx.x & 63;
  const int colid = lane & 15, quad = lane >> 4;

  // XCD swizzle: 768 blocks; lin&7 = XCD; each XCD owns 6 bh entirely.
  const int lin = blockIdx.x;
  const int xcd = lin & 7;
  const int g2  = lin >> 3;            // 0..95
  const int bh  = xcd * 6 + (g2 % 6);
  const int qx  = g2 / 6;              // 0..15
  const int b   = bh / NHEADS, h = bh % NHEADS;
  const int q0  = qx * 64;
  const int base_h = bh * SEQ * DHEAD;

  // Query-side B-frags for 4 q-groups: lane holds B[k=quad*8+j][n=colid].
  bf8 bqf[4][2], btf[4][2], bsf[4][2];
  float rs[4];
#pragma unroll
  for (int g = 0; g < 4; ++g) {
    const int row = q0 + g * 16 + colid;
    const unsigned short* qp = Qb  + base_h + row * 64 + quad * 8;
    const unsigned short* tp = GT1 + base_h + row * 64 + quad * 8;
    const unsigned short* sp = GT2 + base_h + row * 64 + quad * 8;
    bqf[g][0] = *(const bf8*)qp;  bqf[g][1] = *(const bf8*)(qp + 32);
    btf[g][0] = *(const bf8*)tp;  btf[g][1] = *(const bf8*)(tp + 32);
    bsf[g][0] = *(const bf8*)sp;  bsf[g][1] = *(const bf8*)(sp + 32);
    float t2 = 0.f, s2 = 0.f;
#pragma unroll
    for (int fr = 0; fr < 2; ++fr)
#pragma unroll
      for (int j = 0; j < 8; ++j) {
        const float tv = bf2f((unsigned short)btf[g][fr][j]);
        const float sv2 = bf2f((unsigned short)bsf[g][fr][j]);
        t2 += tv * tv; s2 += sv2 * sv2;
      }
    t2 += __shfl_xor(t2, 16); t2 += __shfl_xor(t2, 32);
    s2 += __shfl_xor(s2, 16); s2 += __shfl_xor(s2, 32);
    rs[g] = 1.0f / ((sqrtf(t2) + EPSN) * (sqrtf(s2) + EPSN) * 8.0f);
  }

  float m_[4], l_[4];
  fx4 o[4][4];
#pragma unroll
  for (int g = 0; g < 4; ++g) {
    m_[g] = -1.0e30f; l_[g] = 0.f;
#pragma unroll
    for (int fd = 0; fd < 4; ++fd) o[g][fd] = (fx4){0.f, 0.f, 0.f, 0.f};
  }
  const fx4 zero = (fx4){0.f, 0.f, 0.f, 0.f};

  for (int kb = 0; kb < SEQ; kb += 64) {
    // ---- tile load block (44 loads), pinned above compute ----
    bf8 ak[4][2], at_[4][2], as_[4][2];
    h4 vv[4][4];
    fx4 mk[4];
#pragma unroll
    for (int f = 0; f < 4; ++f) {
      const int key = kb + f * 16 + colid;
      const unsigned short* kp  = GT0 + base_h + key * 64 + quad * 8;
      const unsigned short* tp  = GT1 + base_h + key * 64 + quad * 8;
      const unsigned short* spp = GT2 + base_h + key * 64 + quad * 8;
      ak[f][0]  = *(const bf8*)kp;  ak[f][1]  = *(const bf8*)(kp + 32);
      at_[f][0] = *(const bf8*)tp;  at_[f][1] = *(const bf8*)(tp + 32);
      as_[f][0] = *(const bf8*)spp; as_[f][1] = *(const bf8*)(spp + 32);
#pragma unroll
      for (int fd = 0; fd < 4; ++fd)
        vv[f][fd] = *(const h4*)(Vtf + (size_t)(bh * DHEAD + fd * 16 + colid) * SEQ
                                     + kb + f * 16 + quad * 4);
      mk[f] = *(const fx4*)(maskb + b * SEQ + kb + f * 16 + quad * 4);
    }
    __builtin_amdgcn_sched_barrier(0);   // keep loads issued before compute

    // ---- per q-group: scores^T, softmax, PV ----
#pragma unroll
    for (int g = 0; g < 4; ++g) {
      float sv[4][4];
#pragma unroll
      for (int f = 0; f < 4; ++f) {
        fx4 ab = __builtin_amdgcn_mfma_f32_16x16x32_bf16(ak[f][0], bqf[g][0], zero, 0, 0, 0);
        ab = __builtin_amdgcn_mfma_f32_16x16x32_bf16(ak[f][1], bqf[g][1], ab, 0, 0, 0);
        fx4 tt = __builtin_amdgcn_mfma_f32_16x16x32_bf16(at_[f][0], btf[g][0], zero, 0, 0, 0);
        tt = __builtin_amdgcn_mfma_f32_16x16x32_bf16(at_[f][1], btf[g][1], tt, 0, 0, 0);
        fx4 ss = __builtin_amdgcn_mfma_f32_16x16x32_bf16(as_[f][0], bsf[g][0], zero, 0, 0, 0);
        ss = __builtin_amdgcn_mfma_f32_16x16x32_bf16(as_[f][1], bsf[g][1], ss, 0, 0, 0);
#pragma unroll
        for (int reg = 0; reg < 4; ++reg)
          sv[f][reg] = (ab[reg] * tt[reg]) * ss[reg] * rs[g] + mk[f][reg];
      }

      float bm = sv[0][0];
#pragma unroll
      for (int f = 0; f < 4; ++f)
#pragma unroll
        for (int reg = 0; reg < 4; ++reg) bm = fmaxf(bm, sv[f][reg]);
      bm = fmaxf(bm, __shfl_xor(bm, 16));
      bm = fmaxf(bm, __shfl_xor(bm, 32));
      const float mn = fmaxf(m_[g], bm);
      const float alpha = __expf(m_[g] - mn);
      float rsum = 0.f;
      h4 pa[4];
#pragma unroll
      for (int f = 0; f < 4; ++f)
#pragma unroll
        for (int reg = 0; reg < 4; ++reg) {
          const float p = __expf(sv[f][reg] - mn);
          rsum += p;
          pa[f][reg] = (_Float16)p;
        }
      rsum += __shfl_xor(rsum, 16);
      rsum += __shfl_xor(rsum, 32);
      l_[g] = l_[g] * alpha + rsum;
      m_[g] = mn;

      float ar[4];
#pragma unroll
      for (int reg = 0; reg < 4; ++reg) ar[reg] = __shfl(alpha, quad * 4 + reg);
#pragma unroll
      for (int fd = 0; fd < 4; ++fd)
#pragma unroll
        for (int reg = 0; reg < 4; ++reg) o[g][fd][reg] *= ar[reg];

#pragma unroll
      for (int f = 0; f < 4; ++f)
#pragma unroll
        for (int fd = 0; fd < 4; ++fd)
          o[g][fd] = __builtin_amdgcn_mfma_f32_16x16x16f16(pa[f], vv[f][fd], o[g][fd], 0, 0, 0);
    }
  }

  // Epilogue per group: out[b, s, h*64+d] = O / l  (f32 out).
#pragma unroll
  for (int g = 0; g < 4; ++g) {
    const float linv = 1.0f / l_[g];
    float ir[4];
#pragma unroll
    for (int reg = 0; reg < 4; ++reg) ir[reg] = __shfl(linv, quad * 4 + reg);
#pragma unroll
    for (int reg = 0; reg < 4; ++reg) {
      const int s = q0 + g * 16 + quad * 4 + reg;
#pragma unroll
      for (int fd = 0; fd < 4; ++fd)
        outb[(size_t)(b * SEQ + s) * HDIM + h * DHEAD + fd * 16 + colid] = o[g][fd][reg] * ir[reg];
    }
  }
}

extern "C" void kernel_launch(void* const* d_in, const int* in_sizes, int n_in,
                              void* d_out, int out_size, void* d_ws, size_t ws_size,
                              hipStream_t stream)
{
  (void)in_sizes; (void)n_in; (void)out_size; (void)ws_size;
  const float* hs   = (const float*)d_in[0];
  const float* te   = (const float*)d_in[1];
  const float* se   = (const float*)d_in[2];
  const float* mask = (const float*)d_in[3];
  const float* Wq   = (const float*)d_in[4];
  const float* bq   = (const float*)d_in[5];
  const float* Wk   = (const float*)d_in[6];
  const float* bk   = (const float*)d_in[7];
  const float* Wv   = (const float*)d_in[8];
  const float* bv   = (const float*)d_in[9];
  const float* Wt   = (const float*)d_in[10];
  const float* bt   = (const float*)d_in[11];
  const float* Wsp  = (const float*)d_in[12];
  const float* bsp  = (const float*)d_in[13];
  float* out = (float*)d_out;
  unsigned short* ws = (unsigned short*)d_ws;

  // ws layout (ushort units): Qb@0 Kb@1SZ Tb@2SZ Sb@3SZ Vt(f16)@4SZ
  // convert-phase: hsb@5SZ teb@6SZ seb@7SZ W[5]@8SZ+z*WSZ (dead after proj)
  convert_kernel<<<dim3(1536, 8), 256, 0, stream>>>(hs, te, se, Wq, Wk, Wv, Wt, Wsp, ws);
  proj_qkv_kernel<<<dim3(6, 32), 256, 0, stream>>>(ws, bq, bk, bv);
  proj_ts_kernel<<<dim3(6, 32, 2), 256, 0, stream>>>(ws, bt, bsp);
  attn_kernel<<<dim3(768), 64, 0, stream>>>(ws, mask, out);
}

// Round 7
// 244.516 us; speedup vs baseline: 1.6154x; 1.2179x over previous
//
#include <hip/hip_runtime.h>

#define NHEADS 12
#define SEQ    1024
#define HDIM   768
#define DHEAD  64
#define BH_TOT 48
#define EPSN   1e-6f

typedef __attribute__((ext_vector_type(8))) short    bf8;  // 8 bf16 (4 VGPRs) MFMA A/B frag
typedef __attribute__((ext_vector_type(4))) float    fx4;  // MFMA C/D frag / float4
typedef __attribute__((ext_vector_type(4))) _Float16 h4;   // 4 f16 (2 VGPRs) 16x16x16 frag

#define SZT 3145728u   // 48*1024*64 elements (one head-split tensor)
#define WSZ 589824u    // 768*768 elements (one weight matrix)

__device__ __forceinline__ float bf2f(unsigned short h) {
  union { unsigned int u; float f; } v; v.u = ((unsigned int)h) << 16; return v.f;
}
__device__ __forceinline__ unsigned short f2bf(float f) {
  union { float f; unsigned int u; } v; v.f = f;
  unsigned int u = v.u;
  return (unsigned short)((u + 0x7FFFu + ((u >> 16) & 1u)) >> 16);
}

// async global->LDS, 16B per lane; LDS dest = wave-uniform base + lane*16.
typedef __attribute__((address_space(3))) unsigned int lds_u32;
typedef __attribute__((address_space(1))) const unsigned int glb_u32;
__device__ __forceinline__ void gld16(const unsigned short* g, unsigned short* l) {
  __builtin_amdgcn_global_load_lds((glb_u32*)g, (lds_u32*)l, 16, 0, 0);
}

// ---------------------------------------------------------------------------
// One-shot f32 -> bf16 conversion of X (hs,te,se) and W (q,k,v,t,s) into ws.
// Layout (ushort units): hsb@5SZ teb@6SZ seb@7SZ  W[z]@8SZ + z*WSZ
// ---------------------------------------------------------------------------
__global__ void convert_kernel(const float* __restrict__ hs, const float* __restrict__ te,
                               const float* __restrict__ se,
                               const float* __restrict__ Wq, const float* __restrict__ Wk,
                               const float* __restrict__ Wv, const float* __restrict__ Wt,
                               const float* __restrict__ Ws2,
                               unsigned short* __restrict__ ws)
{
  const int z = blockIdx.y;
  const float* src;
  unsigned short* dst;
  int n;
  if (z < 3) {
    src = (z == 0) ? hs : (z == 1) ? te : se;
    dst = ws + (size_t)(5 + z) * SZT;
    n = 3145728;
  } else {
    src = (z == 3) ? Wq : (z == 4) ? Wk : (z == 5) ? Wv : (z == 6) ? Wt : Ws2;
    dst = ws + (size_t)8 * SZT + (size_t)(z - 3) * WSZ;
    n = 589824;
  }
  const int base = (blockIdx.x * 256 + threadIdx.x) * 8;
  if (base >= n) return;
  const fx4 a = *(const fx4*)(src + base);
  const fx4 b = *(const fx4*)(src + base + 4);
  bf8 o;
#pragma unroll
  for (int j = 0; j < 4; ++j) { o[j] = (short)f2bf(a[j]); o[4 + j] = (short)f2bf(b[j]); }
  *(bf8*)(dst + base) = o;
}

// ---------------------------------------------------------------------------
// Projection GEMM (bf16 in): out = X[4096,768] @ W[768,768]^T + b, head-split.
// Unfused 5-z (960 blocks, ~3/CU). Double-buffered gld16 staging, one barrier
// per K-tile. z: 0=Q 1=K 2=V(f16, transposed Vt[bh*64+d][1024]) 3=T 4=S
// ---------------------------------------------------------------------------
__global__ __launch_bounds__(256, 3)
void proj_kernel(unsigned short* __restrict__ ws,
                 const float* __restrict__ bq, const float* __restrict__ bk,
                 const float* __restrict__ bv, const float* __restrict__ bt,
                 const float* __restrict__ bs)
{
  __shared__ unsigned short Xs[2][4096];
  __shared__ unsigned short Ys[2][4096];

  const int z = blockIdx.z;
  const unsigned short* X = ws + (size_t)5 * SZT + (size_t)((z < 3) ? 0 : (z - 2)) * SZT;
  const unsigned short* W = ws + (size_t)8 * SZT + (size_t)z * WSZ;
  const float* bias = (z == 0) ? bq : (z == 1) ? bk : (z == 2) ? bv : (z == 3) ? bt : bs;
  unsigned short* out = ws + (size_t)((z < 2) ? z : (z == 2) ? 4 : (z == 3) ? 2 : 3) * SZT;

  const int tid   = threadIdx.x;
  const int lane  = tid & 63;
  const int wid   = tid >> 6;
  const int wm    = wid >> 1, wn = wid & 1;
  const int colid = lane & 15, quad = lane >> 4;
  const int m0 = blockIdx.y * 128, n0 = blockIdx.x * 128;

  auto stage = [&](int kt, int pb) {
#pragma unroll
    for (int i = 0; i < 2; ++i) {
      const int slot = i * 256 + tid;        // 0..511, 16B each
      const int row = slot >> 2, ch = slot & 3;
      gld16(X + (m0 + row) * HDIM + kt + ch * 8, &Xs[pb][slot * 8]);
      gld16(W + (n0 + row) * HDIM + kt + ch * 8, &Ys[pb][slot * 8]);
    }
  };

  fx4 acc[4][4];
#pragma unroll
  for (int i = 0; i < 4; ++i)
#pragma unroll
    for (int j = 0; j < 4; ++j) acc[i][j] = (fx4){0.f, 0.f, 0.f, 0.f};

  stage(0, 0);
  __syncthreads();

  for (int it = 0; it < 24; ++it) {
    const int pb = it & 1;
    if (it + 1 < 24) stage((it + 1) * 32, pb ^ 1);

    bf8 af[4], bfr[4];
#pragma unroll
    for (int i = 0; i < 4; ++i)
      af[i] = *(const bf8*)&Xs[pb][(wm * 64 + i * 16 + colid) * 32 + quad * 8];
#pragma unroll
    for (int j = 0; j < 4; ++j)
      bfr[j] = *(const bf8*)&Ys[pb][(wn * 64 + j * 16 + colid) * 32 + quad * 8];
#pragma unroll
    for (int i = 0; i < 4; ++i)
#pragma unroll
      for (int j = 0; j < 4; ++j)
        acc[i][j] = __builtin_amdgcn_mfma_f32_16x16x32_bf16(af[i], bfr[j], acc[i][j], 0, 0, 0);
    __syncthreads();
  }

  // Epilogue. C/D layout: col=lane&15, row=quad*4+reg.
  if (z != 2) {
#pragma unroll
    for (int i = 0; i < 4; ++i) {
      const int r0 = m0 + wm * 64 + i * 16 + quad * 4;
      const int bb = r0 >> 10, s0 = r0 & 1023;
#pragma unroll
      for (int j = 0; j < 4; ++j) {
        const int c = n0 + wn * 64 + j * 16 + colid;
        const int h = c >> 6, d = c & 63;
        const float bvl = bias[c];
        unsigned short* op = out + (((bb * NHEADS + h) * SEQ + s0) * DHEAD + d);
#pragma unroll
        for (int reg = 0; reg < 4; ++reg)
          op[reg * DHEAD] = f2bf(acc[i][j][reg] + bvl);
      }
    }
  } else {
    // V -> f16, transposed: Vt[(bh*64+d)*1024 + s], 4 consecutive s per 8B store.
#pragma unroll
    for (int i = 0; i < 4; ++i) {
      const int r0 = m0 + wm * 64 + i * 16 + quad * 4;
      const int bb = r0 >> 10, s0 = r0 & 1023;
#pragma unroll
      for (int j = 0; j < 4; ++j) {
        const int c = n0 + wn * 64 + j * 16 + colid;
        const int h = c >> 6, d = c & 63;
        const float bvl = bias[c];
        h4 pk;
#pragma unroll
        for (int reg = 0; reg < 4; ++reg)
          pk[reg] = (_Float16)(acc[i][j][reg] + bvl);
        *(h4*)(void*)(out + ((size_t)((bb * NHEADS + h) * DHEAD + d)) * SEQ + s0) = pk;
      }
    }
  }
}

// ---------------------------------------------------------------------------
// Flash attention, wave = 64 q (4 groups of 16), 64-thread blocks, grid 768
// (3 waves/CU), XCD-swizzled. Spill-free restructure of round 6: each 64-key
// tile processed as two 32-key halves with online softmax per half, so the
// live set is query frags (96) + o (64, AGPR) + one half's tile data (72)
// instead of a full tile + full sv (spilled at 256 VGPR cap in round 6).
// Transposed scores => per-lane softmax (2 shfl); P regs feed f16 PV directly.
// ---------------------------------------------------------------------------
__global__ __launch_bounds__(64, 1)
void attn_kernel(const unsigned short* __restrict__ ws,
                 const float* __restrict__ maskb,
                 float* __restrict__ outb)
{
  const unsigned short* Qb  = ws;
  const unsigned short* GT0 = ws + (size_t)1 * SZT;   // K
  const unsigned short* GT1 = ws + (size_t)2 * SZT;   // T
  const unsigned short* GT2 = ws + (size_t)3 * SZT;   // S
  const _Float16* Vtf = (const _Float16*)(ws + (size_t)4 * SZT);

  const int lane  = threadIdx.x & 63;
  const int colid = lane & 15, quad = lane >> 4;

  // XCD swizzle: 768 blocks; lin&7 = XCD; each XCD owns 6 bh entirely.
  const int lin = blockIdx.x;
  const int xcd = lin & 7;
  const int g2  = lin >> 3;            // 0..95
  const int bh  = xcd * 6 + (g2 % 6);
  const int qx  = g2 / 6;              // 0..15
  const int b   = bh / NHEADS, h = bh % NHEADS;
  const int q0  = qx * 64;
  const int base_h = bh * SEQ * DHEAD;

  // Query-side B-frags for 4 q-groups: lane holds B[k=quad*8+j][n=colid].
  bf8 bqf[4][2], btf[4][2], bsf[4][2];
  float rs[4];
#pragma unroll
  for (int g = 0; g < 4; ++g) {
    const int row = q0 + g * 16 + colid;
    const unsigned short* qp = Qb  + base_h + row * 64 + quad * 8;
    const unsigned short* tp = GT1 + base_h + row * 64 + quad * 8;
    const unsigned short* sp = GT2 + base_h + row * 64 + quad * 8;
    bqf[g][0] = *(const bf8*)qp;  bqf[g][1] = *(const bf8*)(qp + 32);
    btf[g][0] = *(const bf8*)tp;  btf[g][1] = *(const bf8*)(tp + 32);
    bsf[g][0] = *(const bf8*)sp;  bsf[g][1] = *(const bf8*)(sp + 32);
    float t2 = 0.f, s2 = 0.f;
#pragma unroll
    for (int fr = 0; fr < 2; ++fr)
#pragma unroll
      for (int j = 0; j < 8; ++j) {
        const float tv = bf2f((unsigned short)btf[g][fr][j]);
        const float sv2 = bf2f((unsigned short)bsf[g][fr][j]);
        t2 += tv * tv; s2 += sv2 * sv2;
      }
    t2 += __shfl_xor(t2, 16); t2 += __shfl_xor(t2, 32);
    s2 += __shfl_xor(s2, 16); s2 += __shfl_xor(s2, 32);
    rs[g] = 1.0f / ((sqrtf(t2) + EPSN) * (sqrtf(s2) + EPSN) * 8.0f);
  }

  float m_[4], l_[4];
  fx4 o[4][4];
#pragma unroll
  for (int g = 0; g < 4; ++g) {
    m_[g] = -1.0e30f; l_[g] = 0.f;
#pragma unroll
    for (int fd = 0; fd < 4; ++fd) o[g][fd] = (fx4){0.f, 0.f, 0.f, 0.f};
  }
  const fx4 zero = (fx4){0.f, 0.f, 0.f, 0.f};

#pragma unroll 1
  for (int kb = 0; kb < SEQ; kb += 64) {
#pragma unroll
    for (int hh = 0; hh < 2; ++hh) {
      // ---- 32-key half: load K/T/S frags + V + mask (72 regs live) ----
      bf8 ak[2][2], at_[2][2], as_[2][2];
      h4 vv[2][4];
      fx4 mk[2];
#pragma unroll
      for (int ff = 0; ff < 2; ++ff) {
        const int f = hh * 2 + ff;
        const int key = kb + f * 16 + colid;
        const unsigned short* kp  = GT0 + base_h + key * 64 + quad * 8;
        const unsigned short* tp  = GT1 + base_h + key * 64 + quad * 8;
        const unsigned short* spp = GT2 + base_h + key * 64 + quad * 8;
        ak[ff][0]  = *(const bf8*)kp;  ak[ff][1]  = *(const bf8*)(kp + 32);
        at_[ff][0] = *(const bf8*)tp;  at_[ff][1] = *(const bf8*)(tp + 32);
        as_[ff][0] = *(const bf8*)spp; as_[ff][1] = *(const bf8*)(spp + 32);
#pragma unroll
        for (int fd = 0; fd < 4; ++fd)
          vv[ff][fd] = *(const h4*)(Vtf + (size_t)(bh * DHEAD + fd * 16 + colid) * SEQ
                                        + kb + f * 16 + quad * 4);
        mk[ff] = *(const fx4*)(maskb + b * SEQ + kb + f * 16 + quad * 4);
      }

      // ---- per q-group: scores^T, online softmax over 32 keys, PV ----
#pragma unroll
      for (int g = 0; g < 4; ++g) {
        float sv[2][4];
#pragma unroll
        for (int ff = 0; ff < 2; ++ff) {
          fx4 ab = __builtin_amdgcn_mfma_f32_16x16x32_bf16(ak[ff][0], bqf[g][0], zero, 0, 0, 0);
          ab = __builtin_amdgcn_mfma_f32_16x16x32_bf16(ak[ff][1], bqf[g][1], ab, 0, 0, 0);
          fx4 tt = __builtin_amdgcn_mfma_f32_16x16x32_bf16(at_[ff][0], btf[g][0], zero, 0, 0, 0);
          tt = __builtin_amdgcn_mfma_f32_16x16x32_bf16(at_[ff][1], btf[g][1], tt, 0, 0, 0);
          fx4 ss = __builtin_amdgcn_mfma_f32_16x16x32_bf16(as_[ff][0], bsf[g][0], zero, 0, 0, 0);
          ss = __builtin_amdgcn_mfma_f32_16x16x32_bf16(as_[ff][1], bsf[g][1], ss, 0, 0, 0);
#pragma unroll
          for (int reg = 0; reg < 4; ++reg)
            sv[ff][reg] = (ab[reg] * tt[reg]) * ss[reg] * rs[g] + mk[ff][reg];
        }

        float bm = sv[0][0];
#pragma unroll
        for (int ff = 0; ff < 2; ++ff)
#pragma unroll
          for (int reg = 0; reg < 4; ++reg) bm = fmaxf(bm, sv[ff][reg]);
        bm = fmaxf(bm, __shfl_xor(bm, 16));
        bm = fmaxf(bm, __shfl_xor(bm, 32));
        const float mn = fmaxf(m_[g], bm);
        const float alpha = __expf(m_[g] - mn);
        float rsum = 0.f;
        h4 pa[2];
#pragma unroll
        for (int ff = 0; ff < 2; ++ff)
#pragma unroll
          for (int reg = 0; reg < 4; ++reg) {
            const float p = __expf(sv[ff][reg] - mn);
            rsum += p;
            pa[ff][reg] = (_Float16)p;
          }
        rsum += __shfl_xor(rsum, 16);
        rsum += __shfl_xor(rsum, 32);
        l_[g] = l_[g] * alpha + rsum;
        m_[g] = mn;

        float ar[4];
#pragma unroll
        for (int reg = 0; reg < 4; ++reg) ar[reg] = __shfl(alpha, quad * 4 + reg);
#pragma unroll
        for (int fd = 0; fd < 4; ++fd)
#pragma unroll
          for (int reg = 0; reg < 4; ++reg) o[g][fd][reg] *= ar[reg];

#pragma unroll
        for (int ff = 0; ff < 2; ++ff)
#pragma unroll
          for (int fd = 0; fd < 4; ++fd)
            o[g][fd] = __builtin_amdgcn_mfma_f32_16x16x16f16(pa[ff], vv[ff][fd], o[g][fd], 0, 0, 0);
      }
    }
  }

  // Epilogue per group: out[b, s, h*64+d] = O / l  (f32 out).
#pragma unroll
  for (int g = 0; g < 4; ++g) {
    const float linv = 1.0f / l_[g];
    float ir[4];
#pragma unroll
    for (int reg = 0; reg < 4; ++reg) ir[reg] = __shfl(linv, quad * 4 + reg);
#pragma unroll
    for (int reg = 0; reg < 4; ++reg) {
      const int s = q0 + g * 16 + quad * 4 + reg;
#pragma unroll
      for (int fd = 0; fd < 4; ++fd)
        outb[(size_t)(b * SEQ + s) * HDIM + h * DHEAD + fd * 16 + colid] = o[g][fd][reg] * ir[reg];
    }
  }
}

extern "C" void kernel_launch(void* const* d_in, const int* in_sizes, int n_in,
                              void* d_out, int out_size, void* d_ws, size_t ws_size,
                              hipStream_t stream)
{
  (void)in_sizes; (void)n_in; (void)out_size; (void)ws_size;
  const float* hs   = (const float*)d_in[0];
  const float* te   = (const float*)d_in[1];
  const float* se   = (const float*)d_in[2];
  const float* mask = (const float*)d_in[3];
  const float* Wq   = (const float*)d_in[4];
  const float* bq   = (const float*)d_in[5];
  const float* Wk   = (const float*)d_in[6];
  const float* bk   = (const float*)d_in[7];
  const float* Wv   = (const float*)d_in[8];
  const float* bv   = (const float*)d_in[9];
  const float* Wt   = (const float*)d_in[10];
  const float* bt   = (const float*)d_in[11];
  const float* Wsp  = (const float*)d_in[12];
  const float* bsp  = (const float*)d_in[13];
  float* out = (float*)d_out;
  unsigned short* ws = (unsigned short*)d_ws;

  // ws layout (ushort units): Qb@0 Kb@1SZ Tb@2SZ Sb@3SZ Vt(f16)@4SZ
  // convert-phase: hsb@5SZ teb@6SZ seb@7SZ W[5]@8SZ+z*WSZ (dead after proj)
  convert_kernel<<<dim3(1536, 8), 256, 0, stream>>>(hs, te, se, Wq, Wk, Wv, Wt, Wsp, ws);
  proj_kernel<<<dim3(6, 32, 5), 256, 0, stream>>>(ws, bq, bk, bv, bt, bsp);
  attn_kernel<<<dim3(768), 64, 0, stream>>>(ws, mask, out);
}